// Round 4
// baseline (855.340 us; speedup 1.0000x reference)
//
#include <hip/hip_runtime.h>
#include <hip/hip_bf16.h>
#include <stdint.h>

#define LATF 256
#define NT 119
#define NNODES 100000
#define NEDGES 400000

typedef __attribute__((ext_vector_type(8))) short short8;
typedef __attribute__((ext_vector_type(4))) float f4;

__device__ __forceinline__ float bf2f(short u) {
  union { uint32_t i; float f; } v; v.i = ((uint32_t)(uint16_t)u) << 16; return v.f;
}
__device__ __forceinline__ short f2bf(float f) {
  union { float f; uint32_t i; } v; v.f = f;
  uint32_t r = (v.i + 0x7fffu + ((v.i >> 16) & 1u)) >> 16;
  return (short)(uint16_t)r;
}

// ---------------- prep: cast + build transposed weight layouts ----------------
__global__ __launch_bounds__(256) void prep_kernel(
    const float* __restrict__ lat, const float* __restrict__ pos,
    const float* __restrict__ nW1, const float* __restrict__ tW1, const float* __restrict__ dW1,
    const float* __restrict__ nW2, const float* __restrict__ tW2, const float* __restrict__ dW2,
    const float* __restrict__ nW3, const float* __restrict__ dW3,
    short* __restrict__ latent_bf, short* __restrict__ pos_bf,
    short* __restrict__ Wtcat, short* __restrict__ Wt2cat,
    short* __restrict__ Wt3n, float* __restrict__ dW3p)
{
  int i = blockIdx.x * 256 + threadIdx.x;
  if (i < 524288) { latent_bf[i] = f2bf(lat[i]); return; }
  i -= 524288;
  if (i < 800000) { pos_bf[i] = f2bf(pos[i]); return; }
  i -= 800000;
  if (i < 1280 * 288) {               // Wtcat[n][k], n-major, K padded 264->288
    int n = i / 288, k = i % 288;
    float v = 0.f;
    if (k < 264) {
      if (n < 256)       v = nW1[k * 256 + n];
      else if (n < 512)  v = tW1[k * 256 + (n - 256)];
      else if (n < 768)  v = tW1[(264 + k) * 256 + (n - 512)];
      else if (n < 1024) v = dW1[k * 256 + (n - 768)];
      else               v = dW1[(264 + k) * 256 + (n - 1024)];
    }
    Wtcat[n * 288 + k] = f2bf(v);
    return;
  }
  i -= 1280 * 288;
  if (i < 384 * 256) {                // Wt2cat[n][k]: rows 0-127 nW2, 128-255 tW2, 256-383 dW2
    int n = i / 256, k = i % 256;
    float v = (n < 128) ? nW2[k * 128 + n] : (n < 256) ? tW2[k * 128 + (n - 128)]
                                                       : dW2[k * 128 + (n - 256)];
    Wt2cat[n * 256 + k] = f2bf(v);
    return;
  }
  i -= 384 * 256;
  if (i < 128 * 128) {                // Wt3n[n][k], n padded 119->128
    int n = i / 128, k = i % 128;
    Wt3n[i] = (n < NT) ? f2bf(nW3[k * NT + n]) : (short)0;
    return;
  }
  i -= 128 * 128;
  if (i < 512) {                      // dW3p[k][4] f32, col 3 zero-padded
    int k = i >> 2, n = i & 3;
    dW3p[i] = (n < 3) ? dW3[k * 3 + n] : 0.f;
    return;
  }
}

// ---------------- K1: nodeFeat x [nW1 | tW1_src | tW1_dst | dW1_src | dW1_dst] ----------------
// M=100000, K=288 (pad), N=1280. BM=128, BN=128, 4 waves (2x2), each wave 64x64.
// Epilogue writes Pall in k3's layout: [t_src | d_src | t_dst | d_dst], with
// tb1 folded into t_src and db1 folded into d_src.
__global__ __launch_bounds__(256) void k1_gemm(
    const short* __restrict__ latent_bf, const short* __restrict__ pos_bf,
    const int* __restrict__ batch, const short* __restrict__ Wtcat,
    const float* __restrict__ nb1, const float* __restrict__ tb1, const float* __restrict__ db1,
    short* __restrict__ h1_node, short* __restrict__ Pall)
{
  __shared__ short As[128 * 40];   // 32 K-elems + pad 8 -> row stride 80B
  const int t = threadIdx.x;
  const int bm0 = blockIdx.x * 128;
  const int n0 = blockIdx.y * 128;
  const int wid = t >> 6, lane = t & 63;
  const int wm = wid >> 1, wn = wid & 1;
  const int lrow = lane & 15, kq = lane >> 4;

  const int sr = t >> 1, sq = t & 1;          // staging: 2 threads per row, 16 cols each
  const int m_stage = bm0 + sr;
  const bool svalid = (m_stage < NNODES);
  const int g = svalid ? batch[m_stage] : 0;

  f4 acc[4][4];
  #pragma unroll
  for (int a = 0; a < 4; ++a)
    #pragma unroll
    for (int b = 0; b < 4; ++b) acc[a][b] = (f4){0.f, 0.f, 0.f, 0.f};

  for (int kc = 0; kc < 9; ++kc) {
    const int k0 = kc * 32;
    short8 av0 = {0,0,0,0,0,0,0,0}, av1 = {0,0,0,0,0,0,0,0};
    if (svalid) {
      const int col = k0 + sq * 16;
      if (col < 256) {
        av0 = *(const short8*)(latent_bf + g * 256 + col);
        av1 = *(const short8*)(latent_bf + g * 256 + col + 8);
      } else if (sq == 0) {
        av0 = *(const short8*)(pos_bf + m_stage * 8);
      }
    }
    *(short8*)(As + sr * 40 + sq * 16) = av0;
    *(short8*)(As + sr * 40 + sq * 16 + 8) = av1;
    __syncthreads();

    short8 af[4];
    #pragma unroll
    for (int mf = 0; mf < 4; ++mf)
      af[mf] = *(const short8*)(As + (wm * 64 + mf * 16 + lrow) * 40 + kq * 8);
    #pragma unroll
    for (int nf = 0; nf < 4; ++nf) {
      const int ncol = n0 + wn * 64 + nf * 16 + lrow;
      short8 bfv = *(const short8*)(Wtcat + ncol * 288 + k0 + kq * 8);
      #pragma unroll
      for (int mf = 0; mf < 4; ++mf)
        acc[mf][nf] = __builtin_amdgcn_mfma_f32_16x16x32_bf16(af[mf], bfv, acc[mf][nf], 0, 0, 0);
    }
    __syncthreads();
  }

  #pragma unroll
  for (int mf = 0; mf < 4; ++mf)
    #pragma unroll
    for (int nf = 0; nf < 4; ++nf) {
      const int nglob = n0 + wn * 64 + nf * 16 + lrow;
      #pragma unroll
      for (int r = 0; r < 4; ++r) {
        const int m = bm0 + wm * 64 + mf * 16 + kq * 4 + r;
        if (m < NNODES) {
          float v = acc[mf][nf][r];
          if (nglob < 256) {
            float h = v + nb1[nglob];
            h1_node[m * 256 + nglob] = f2bf(h > 0.f ? h : 0.f);
          } else {
            // GEMM column order: [t_src | t_dst | d_src | d_dst] -> Pall [t_src | d_src | t_dst | d_dst]
            const int pc = nglob - 256;
            float vv = v;
            int newc = pc;
            if (pc < 256)       { vv += tb1[pc]; }                    // t_src -> 0:256
            else if (pc < 512)  { newc = pc + 256; }                  // t_dst -> 512:768
            else if (pc < 768)  { vv += db1[pc - 512]; newc = pc - 256; } // d_src -> 256:512
            /* else d_dst stays at 768:1024 */
            Pall[m * 1024 + newc] = f2bf(vv);
          }
        }
      }
    }
}

// ---------------- K2: node tail 256 -> 128(relu) -> 119 ----------------
__global__ __launch_bounds__(256) void k2_node_tail(
    const short* __restrict__ h1_node, const short* __restrict__ Wt2cat,
    const short* __restrict__ Wt3n, const float* __restrict__ nb2,
    const float* __restrict__ nb3, float* __restrict__ out_node)
{
  __shared__ short h2s[64 * 136];
  const int t = threadIdx.x;
  const int bm0 = blockIdx.x * 64;
  const int wid = t >> 6, lane = t & 63;
  const int wm = wid >> 1, wn = wid & 1;
  const int lrow = lane & 15, kq = lane >> 4;

  f4 acc[2][4];
  #pragma unroll
  for (int a = 0; a < 2; ++a)
    #pragma unroll
    for (int b = 0; b < 4; ++b) acc[a][b] = (f4){0.f, 0.f, 0.f, 0.f};

  #pragma unroll
  for (int kc = 0; kc < 8; ++kc) {
    short8 af[2];
    #pragma unroll
    for (int mf = 0; mf < 2; ++mf) {
      const int m = bm0 + wm * 32 + mf * 16 + lrow;
      if (m < NNODES) af[mf] = *(const short8*)(h1_node + m * 256 + kc * 32 + kq * 8);
      else            af[mf] = (short8){0, 0, 0, 0, 0, 0, 0, 0};
    }
    #pragma unroll
    for (int nf = 0; nf < 4; ++nf) {
      const int ncol = wn * 64 + nf * 16 + lrow;
      short8 bfv = *(const short8*)(Wt2cat + ncol * 256 + kc * 32 + kq * 8);
      acc[0][nf] = __builtin_amdgcn_mfma_f32_16x16x32_bf16(af[0], bfv, acc[0][nf], 0, 0, 0);
      acc[1][nf] = __builtin_amdgcn_mfma_f32_16x16x32_bf16(af[1], bfv, acc[1][nf], 0, 0, 0);
    }
  }
  #pragma unroll
  for (int mf = 0; mf < 2; ++mf)
    #pragma unroll
    for (int nf = 0; nf < 4; ++nf) {
      const int n = wn * 64 + nf * 16 + lrow;
      #pragma unroll
      for (int r = 0; r < 4; ++r) {
        const int ml = wm * 32 + mf * 16 + kq * 4 + r;
        float h = acc[mf][nf][r] + nb2[n];
        h2s[ml * 136 + n] = f2bf(h > 0.f ? h : 0.f);
      }
    }
  __syncthreads();

  f4 acc2[2][4];
  #pragma unroll
  for (int a = 0; a < 2; ++a)
    #pragma unroll
    for (int b = 0; b < 4; ++b) acc2[a][b] = (f4){0.f, 0.f, 0.f, 0.f};

  #pragma unroll
  for (int kc = 0; kc < 4; ++kc) {
    short8 af[2];
    #pragma unroll
    for (int mf = 0; mf < 2; ++mf)
      af[mf] = *(const short8*)(h2s + (wm * 32 + mf * 16 + lrow) * 136 + kc * 32 + kq * 8);
    #pragma unroll
    for (int nf = 0; nf < 4; ++nf) {
      const int ncol = wn * 64 + nf * 16 + lrow;
      short8 bfv = *(const short8*)(Wt3n + ncol * 128 + kc * 32 + kq * 8);
      acc2[0][nf] = __builtin_amdgcn_mfma_f32_16x16x32_bf16(af[0], bfv, acc2[0][nf], 0, 0, 0);
      acc2[1][nf] = __builtin_amdgcn_mfma_f32_16x16x32_bf16(af[1], bfv, acc2[1][nf], 0, 0, 0);
    }
  }
  #pragma unroll
  for (int mf = 0; mf < 2; ++mf)
    #pragma unroll
    for (int nf = 0; nf < 4; ++nf) {
      const int n = wn * 64 + nf * 16 + lrow;
      #pragma unroll
      for (int r = 0; r < 4; ++r) {
        const int m = bm0 + wm * 32 + mf * 16 + kq * 4 + r;
        if (m < NNODES && n < NT) out_node[m * NT + n] = acc2[mf][nf][r] + nb3[n];
      }
    }
}

// ---------------- K3: edge tail, zero-LDS, zero-barrier; wave = 16 edges ----------------
// Gather lands directly in MFMA A-fragment layout (lane l: edge l&15, cols (l>>4)*8 + 32c).
// B-fragments from global (identical addresses across waves -> L1-hot).
// Layer-3 from f32 accumulators via 16-lane shfl_xor butterfly; no LDS anywhere.
__global__ __launch_bounds__(256) void k3_edge(
    const short* __restrict__ Pall, const int* __restrict__ eidx,
    const short* __restrict__ Wt2cat,
    const float* __restrict__ tb2, const float* __restrict__ db2,
    const float* __restrict__ tW3, const float* __restrict__ dW3p,
    const float* __restrict__ tb3, const float* __restrict__ db3,
    float* __restrict__ out_t, float* __restrict__ out_d)
{
  const int t = threadIdx.x;
  const int wid = t >> 6, lane = t & 63;
  const int e0w = blockIdx.x * 64 + wid * 16;   // NEDGES = 6250*64 exactly
  const int er = lane & 15, kq = lane >> 4;     // A-frag: row (edge) = er, k-quarter = kq

  const int s_idx = eidx[e0w + er];
  const int d_idx = eidx[NEDGES + e0w + er];
  const short* Ps = Pall + (long)s_idx * 1024 + kq * 8;        // src: [t_src|d_src]
  const short* Pd = Pall + (long)d_idx * 1024 + 512 + kq * 8;  // dst: [t_dst|d_dst]

  // ---- type gather (16 loads in flight) ----
  short8 ts[8], tdv[8];
  #pragma unroll
  for (int c = 0; c < 8; ++c) ts[c] = *(const short8*)(Ps + c * 32);
  #pragma unroll
  for (int c = 0; c < 8; ++c) tdv[c] = *(const short8*)(Pd + c * 32);
  short8 h1t[8];
  #pragma unroll
  for (int c = 0; c < 8; ++c) {
    short8 o;
    #pragma unroll
    for (int x = 0; x < 8; ++x) {
      float f = bf2f(ts[c][x]) + bf2f(tdv[c][x]);
      o[x] = f2bf(f > 0.f ? f : 0.f);
    }
    h1t[c] = o;
  }

  // ---- dir gather: issue now, consumed after type GEMM (latency hidden by MFMA) ----
  short8 es[8], ed[8];
  #pragma unroll
  for (int c = 0; c < 8; ++c) es[c] = *(const short8*)(Ps + 256 + c * 32);
  #pragma unroll
  for (int c = 0; c < 8; ++c) ed[c] = *(const short8*)(Pd + 256 + c * 32);

  // ---- type GEMM: h1t[16x256] @ tW2 (Wt2cat rows 128:256) ----
  f4 acc_t[8];
  #pragma unroll
  for (int nf = 0; nf < 8; ++nf) acc_t[nf] = (f4){0.f, 0.f, 0.f, 0.f};
  #pragma unroll
  for (int kc = 0; kc < 8; ++kc) {
    #pragma unroll
    for (int nf = 0; nf < 8; ++nf) {
      short8 bfv = *(const short8*)(Wt2cat + (128 + nf * 16 + er) * 256 + kc * 32 + kq * 8);
      acc_t[nf] = __builtin_amdgcn_mfma_f32_16x16x32_bf16(h1t[kc], bfv, acc_t[nf], 0, 0, 0);
    }
  }

  // ---- dir combine + GEMM: Wt2cat rows 256:384 ----
  short8 h1d[8];
  #pragma unroll
  for (int c = 0; c < 8; ++c) {
    short8 o;
    #pragma unroll
    for (int x = 0; x < 8; ++x) {
      float f = bf2f(es[c][x]) + bf2f(ed[c][x]);
      o[x] = f2bf(f > 0.f ? f : 0.f);
    }
    h1d[c] = o;
  }
  f4 acc_d[8];
  #pragma unroll
  for (int nf = 0; nf < 8; ++nf) acc_d[nf] = (f4){0.f, 0.f, 0.f, 0.f};
  #pragma unroll
  for (int kc = 0; kc < 8; ++kc) {
    #pragma unroll
    for (int nf = 0; nf < 8; ++nf) {
      short8 bfv = *(const short8*)(Wt2cat + (256 + nf * 16 + er) * 256 + kc * 32 + kq * 8);
      acc_d[nf] = __builtin_amdgcn_mfma_f32_16x16x32_bf16(h1d[kc], bfv, acc_d[nf], 0, 0, 0);
    }
  }

  // ---- h2 = relu(acc + b2) in f32 regs; C layout: col = er(=lane&15), row = kq*4 + r ----
  float ht[8][4], hd[8][4];
  #pragma unroll
  for (int nf = 0; nf < 8; ++nf) {
    const float bt = tb2[nf * 16 + er];
    const float bd = db2[nf * 16 + er];
    #pragma unroll
    for (int r = 0; r < 4; ++r) {
      float a = acc_t[nf][r] + bt; ht[nf][r] = a > 0.f ? a : 0.f;
      float b = acc_d[nf][r] + bd; hd[nf][r] = b > 0.f ? b : 0.f;
    }
  }

  // ---- layer-3 partials: this lane covers h2 col (nf*16 + er) ----
  float pt[4][4], pd[3][4];
  #pragma unroll
  for (int n = 0; n < 4; ++n)
    #pragma unroll
    for (int r = 0; r < 4; ++r) pt[n][r] = 0.f;
  #pragma unroll
  for (int n = 0; n < 3; ++n)
    #pragma unroll
    for (int r = 0; r < 4; ++r) pd[n][r] = 0.f;

  #pragma unroll
  for (int nf = 0; nf < 8; ++nf) {
    f4 wt = ((const f4*)tW3)[nf * 16 + er];    // tW3 is f32 [128][4] row-major
    f4 wd = ((const f4*)dW3p)[nf * 16 + er];   // dW3p is f32 [128][4], col3 = 0
    #pragma unroll
    for (int r = 0; r < 4; ++r) {
      #pragma unroll
      for (int n = 0; n < 4; ++n) pt[n][r] += ht[nf][r] * wt[n];
      #pragma unroll
      for (int n = 0; n < 3; ++n) pd[n][r] += hd[nf][r] * wd[n];
    }
  }

  // ---- butterfly reduce over the 16 column-lanes (masks stay within 16-lane group) ----
  #pragma unroll
  for (int mask = 1; mask < 16; mask <<= 1) {
    #pragma unroll
    for (int n = 0; n < 4; ++n)
      #pragma unroll
      for (int r = 0; r < 4; ++r) pt[n][r] += __shfl_xor(pt[n][r], mask, 64);
    #pragma unroll
    for (int n = 0; n < 3; ++n)
      #pragma unroll
      for (int r = 0; r < 4; ++r) pd[n][r] += __shfl_xor(pd[n][r], mask, 64);
  }

  // ---- write: lane er<4 -> type col er; lane 4<=er<7 -> dir col er-4 ----
  if (er < 4) {
    const float b = tb3[er];
    #pragma unroll
    for (int r = 0; r < 4; ++r)
      out_t[(e0w + kq * 4 + r) * 4 + er] = pt[er][r] + b;
  } else if (er < 7) {
    const int n = er - 4;
    const float b = db3[n];
    #pragma unroll
    for (int r = 0; r < 4; ++r)
      out_d[(e0w + kq * 4 + r) * 3 + n] = pd[n][r] + b;
  }
}

extern "C" void kernel_launch(void* const* d_in, const int* in_sizes, int n_in,
                              void* d_out, int out_size, void* d_ws, size_t ws_size,
                              hipStream_t stream)
{
  const float* lat = (const float*)d_in[0];
  const float* pos = (const float*)d_in[1];
  const int* batch = (const int*)d_in[2];
  const int* eidx  = (const int*)d_in[3];
  const float* nW1 = (const float*)d_in[4];  const float* nb1 = (const float*)d_in[5];
  const float* nW2 = (const float*)d_in[6];  const float* nb2 = (const float*)d_in[7];
  const float* nW3 = (const float*)d_in[8];  const float* nb3 = (const float*)d_in[9];
  const float* tW1 = (const float*)d_in[10]; const float* tb1 = (const float*)d_in[11];
  const float* tW2 = (const float*)d_in[12]; const float* tb2 = (const float*)d_in[13];
  const float* tW3 = (const float*)d_in[14]; const float* tb3 = (const float*)d_in[15];
  const float* dW1 = (const float*)d_in[16]; const float* db1 = (const float*)d_in[17];
  const float* dW2 = (const float*)d_in[18]; const float* db2 = (const float*)d_in[19];
  const float* dW3 = (const float*)d_in[20]; const float* db3 = (const float*)d_in[21];

  char* ws = (char*)d_ws;
  short* latent_bf = (short*)(ws + 0);          //   1,048,576 B
  short* pos_bf    = (short*)(ws + 1048576);    //   1,600,000 B
  short* Wtcat     = (short*)(ws + 2648576);    //     737,280 B
  short* Wt2cat    = (short*)(ws + 3385856);    //     196,608 B
  short* Wt3n      = (short*)(ws + 3582464);    //      32,768 B
  float* dW3p      = (float*)(ws + 3615232);    //       2,048 B
  short* h1_node   = (short*)(ws + 3617280);    //  51,200,000 B
  short* Pall      = (short*)(ws + 54817280);   // 204,800,000 B  -> total ~259.6 MB

  float* out_node = (float*)d_out;
  float* out_t = out_node + (size_t)NNODES * NT;
  float* out_d = out_t + (size_t)NEDGES * 4;

  prep_kernel<<<7063, 256, 0, stream>>>(lat, pos, nW1, tW1, dW1, nW2, tW2, dW2,
                                        nW3, dW3, latent_bf, pos_bf, Wtcat,
                                        Wt2cat, Wt3n, dW3p);
  k1_gemm<<<dim3(782, 10), 256, 0, stream>>>(latent_bf, pos_bf, batch, Wtcat,
                                             nb1, tb1, db1, h1_node, Pall);
  k2_node_tail<<<1563, 256, 0, stream>>>(h1_node, Wt2cat, Wt3n, nb2, nb3, out_node);
  k3_edge<<<6250, 256, 0, stream>>>(Pall, eidx, Wt2cat,
                                    tb2, db2, tW3, dW3p, tb3, db3, out_t, out_d);
}

// Round 5
// 808.781 us; speedup vs baseline: 1.0576x; 1.0576x over previous
//
#include <hip/hip_runtime.h>
#include <hip/hip_bf16.h>
#include <stdint.h>

#define LATF 256
#define NT 119
#define NNODES 100000
#define NEDGES 400000

#define K3_GRID 512
#define K3_TILES 25000   // 400000 / 16

typedef __attribute__((ext_vector_type(8))) short short8;
typedef __attribute__((ext_vector_type(4))) float f4;

__device__ __forceinline__ float bf2f(short u) {
  union { uint32_t i; float f; } v; v.i = ((uint32_t)(uint16_t)u) << 16; return v.f;
}
__device__ __forceinline__ short f2bf(float f) {
  union { float f; uint32_t i; } v; v.f = f;
  uint32_t r = (v.i + 0x7fffu + ((v.i >> 16) & 1u)) >> 16;
  return (short)(uint16_t)r;
}

// ---------------- prep: cast + build transposed weight layouts ----------------
__global__ __launch_bounds__(256) void prep_kernel(
    const float* __restrict__ lat, const float* __restrict__ pos,
    const float* __restrict__ nW1, const float* __restrict__ tW1, const float* __restrict__ dW1,
    const float* __restrict__ nW2, const float* __restrict__ tW2, const float* __restrict__ dW2,
    const float* __restrict__ nW3, const float* __restrict__ dW3,
    short* __restrict__ latent_bf, short* __restrict__ pos_bf,
    short* __restrict__ Wtcat, short* __restrict__ Wt2cat,
    short* __restrict__ Wt3n, float* __restrict__ dW3p)
{
  int i = blockIdx.x * 256 + threadIdx.x;
  if (i < 524288) { latent_bf[i] = f2bf(lat[i]); return; }
  i -= 524288;
  if (i < 800000) { pos_bf[i] = f2bf(pos[i]); return; }
  i -= 800000;
  if (i < 1280 * 288) {               // Wtcat[n][k], n-major, K padded 264->288
    int n = i / 288, k = i % 288;
    float v = 0.f;
    if (k < 264) {
      if (n < 256)       v = nW1[k * 256 + n];
      else if (n < 512)  v = tW1[k * 256 + (n - 256)];
      else if (n < 768)  v = tW1[(264 + k) * 256 + (n - 512)];
      else if (n < 1024) v = dW1[k * 256 + (n - 768)];
      else               v = dW1[(264 + k) * 256 + (n - 1024)];
    }
    Wtcat[n * 288 + k] = f2bf(v);
    return;
  }
  i -= 1280 * 288;
  if (i < 384 * 256) {                // Wt2cat[n][k]: rows 0-127 nW2, 128-255 tW2, 256-383 dW2
    int n = i / 256, k = i % 256;
    float v = (n < 128) ? nW2[k * 128 + n] : (n < 256) ? tW2[k * 128 + (n - 128)]
                                                       : dW2[k * 128 + (n - 256)];
    Wt2cat[n * 256 + k] = f2bf(v);
    return;
  }
  i -= 384 * 256;
  if (i < 128 * 128) {                // Wt3n[n][k], n padded 119->128
    int n = i / 128, k = i % 128;
    Wt3n[i] = (n < NT) ? f2bf(nW3[k * NT + n]) : (short)0;
    return;
  }
  i -= 128 * 128;
  if (i < 512) {                      // dW3p[k][4] f32, col 3 zero-padded
    int k = i >> 2, n = i & 3;
    dW3p[i] = (n < 3) ? dW3[k * 3 + n] : 0.f;
    return;
  }
}

// ---------------- K1: nodeFeat x [nW1 | tW1_src | tW1_dst | dW1_src | dW1_dst] ----------------
// M=100000, K=288 (pad), N=1280. BM=64, BN=128, 4 waves (2x2), each wave 32x64. (R3 proven)
// Epilogue writes Pall layout [t_src | d_src | t_dst | d_dst]; tb1 folded into t_src,
// db1 into d_src.
__global__ __launch_bounds__(256) void k1_gemm(
    const short* __restrict__ latent_bf, const short* __restrict__ pos_bf,
    const int* __restrict__ batch, const short* __restrict__ Wtcat,
    const float* __restrict__ nb1, const float* __restrict__ tb1, const float* __restrict__ db1,
    short* __restrict__ h1_node, short* __restrict__ Pall)
{
  __shared__ short As[64 * 40];
  const int t = threadIdx.x;
  const int bm0 = blockIdx.x * 64;
  const int n0 = blockIdx.y * 128;
  const int wid = t >> 6, lane = t & 63;
  const int wm = wid >> 1, wn = wid & 1;
  const int lrow = lane & 15, kq = lane >> 4;

  const int sr = t >> 2, sq = t & 3;
  const int m_stage = bm0 + sr;
  const bool svalid = (m_stage < NNODES);
  const int g = svalid ? batch[m_stage] : 0;

  f4 acc[2][4];
  #pragma unroll
  for (int a = 0; a < 2; ++a)
    #pragma unroll
    for (int b = 0; b < 4; ++b) acc[a][b] = (f4){0.f, 0.f, 0.f, 0.f};

  for (int kc = 0; kc < 9; ++kc) {
    const int k0 = kc * 32;
    short8 av = {0, 0, 0, 0, 0, 0, 0, 0};
    if (svalid) {
      if (k0 < 256)      av = *(const short8*)(latent_bf + g * 256 + k0 + sq * 8);
      else if (sq == 0)  av = *(const short8*)(pos_bf + m_stage * 8);
    }
    *(short8*)(As + sr * 40 + sq * 8) = av;
    __syncthreads();

    short8 af[2];
    #pragma unroll
    for (int mf = 0; mf < 2; ++mf)
      af[mf] = *(const short8*)(As + (wm * 32 + mf * 16 + lrow) * 40 + kq * 8);
    #pragma unroll
    for (int nf = 0; nf < 4; ++nf) {
      const int ncol = n0 + wn * 64 + nf * 16 + lrow;
      short8 bfv = *(const short8*)(Wtcat + ncol * 288 + k0 + kq * 8);
      acc[0][nf] = __builtin_amdgcn_mfma_f32_16x16x32_bf16(af[0], bfv, acc[0][nf], 0, 0, 0);
      acc[1][nf] = __builtin_amdgcn_mfma_f32_16x16x32_bf16(af[1], bfv, acc[1][nf], 0, 0, 0);
    }
    __syncthreads();
  }

  #pragma unroll
  for (int mf = 0; mf < 2; ++mf)
    #pragma unroll
    for (int nf = 0; nf < 4; ++nf) {
      const int nglob = n0 + wn * 64 + nf * 16 + lrow;
      #pragma unroll
      for (int r = 0; r < 4; ++r) {
        const int m = bm0 + wm * 32 + mf * 16 + kq * 4 + r;
        if (m < NNODES) {
          float v = acc[mf][nf][r];
          if (nglob < 256) {
            float h = v + nb1[nglob];
            h1_node[m * 256 + nglob] = f2bf(h > 0.f ? h : 0.f);
          } else {
            const int pc = nglob - 256;
            float vv = v;
            int newc = pc;
            if (pc < 256)       { vv += tb1[pc]; }                       // t_src -> 0:256
            else if (pc < 512)  { newc = pc + 256; }                     // t_dst -> 512:768
            else if (pc < 768)  { vv += db1[pc - 512]; newc = pc - 256; } // d_src -> 256:512
            Pall[m * 1024 + newc] = f2bf(vv);
          }
        }
      }
    }
}

// ---------------- K2: node tail 256 -> 128(relu) -> 119 ----------------
__global__ __launch_bounds__(256) void k2_node_tail(
    const short* __restrict__ h1_node, const short* __restrict__ Wt2cat,
    const short* __restrict__ Wt3n, const float* __restrict__ nb2,
    const float* __restrict__ nb3, float* __restrict__ out_node)
{
  __shared__ short h2s[64 * 136];
  const int t = threadIdx.x;
  const int bm0 = blockIdx.x * 64;
  const int wid = t >> 6, lane = t & 63;
  const int wm = wid >> 1, wn = wid & 1;
  const int lrow = lane & 15, kq = lane >> 4;

  f4 acc[2][4];
  #pragma unroll
  for (int a = 0; a < 2; ++a)
    #pragma unroll
    for (int b = 0; b < 4; ++b) acc[a][b] = (f4){0.f, 0.f, 0.f, 0.f};

  #pragma unroll
  for (int kc = 0; kc < 8; ++kc) {
    short8 af[2];
    #pragma unroll
    for (int mf = 0; mf < 2; ++mf) {
      const int m = bm0 + wm * 32 + mf * 16 + lrow;
      if (m < NNODES) af[mf] = *(const short8*)(h1_node + m * 256 + kc * 32 + kq * 8);
      else            af[mf] = (short8){0, 0, 0, 0, 0, 0, 0, 0};
    }
    #pragma unroll
    for (int nf = 0; nf < 4; ++nf) {
      const int ncol = wn * 64 + nf * 16 + lrow;
      short8 bfv = *(const short8*)(Wt2cat + ncol * 256 + kc * 32 + kq * 8);
      acc[0][nf] = __builtin_amdgcn_mfma_f32_16x16x32_bf16(af[0], bfv, acc[0][nf], 0, 0, 0);
      acc[1][nf] = __builtin_amdgcn_mfma_f32_16x16x32_bf16(af[1], bfv, acc[1][nf], 0, 0, 0);
    }
  }
  #pragma unroll
  for (int mf = 0; mf < 2; ++mf)
    #pragma unroll
    for (int nf = 0; nf < 4; ++nf) {
      const int n = wn * 64 + nf * 16 + lrow;
      #pragma unroll
      for (int r = 0; r < 4; ++r) {
        const int ml = wm * 32 + mf * 16 + kq * 4 + r;
        float h = acc[mf][nf][r] + nb2[n];
        h2s[ml * 136 + n] = f2bf(h > 0.f ? h : 0.f);
      }
    }
  __syncthreads();

  f4 acc2[2][4];
  #pragma unroll
  for (int a = 0; a < 2; ++a)
    #pragma unroll
    for (int b = 0; b < 4; ++b) acc2[a][b] = (f4){0.f, 0.f, 0.f, 0.f};

  #pragma unroll
  for (int kc = 0; kc < 4; ++kc) {
    short8 af[2];
    #pragma unroll
    for (int mf = 0; mf < 2; ++mf)
      af[mf] = *(const short8*)(h2s + (wm * 32 + mf * 16 + lrow) * 136 + kc * 32 + kq * 8);
    #pragma unroll
    for (int nf = 0; nf < 4; ++nf) {
      const int ncol = wn * 64 + nf * 16 + lrow;
      short8 bfv = *(const short8*)(Wt3n + ncol * 128 + kc * 32 + kq * 8);
      acc2[0][nf] = __builtin_amdgcn_mfma_f32_16x16x32_bf16(af[0], bfv, acc2[0][nf], 0, 0, 0);
      acc2[1][nf] = __builtin_amdgcn_mfma_f32_16x16x32_bf16(af[1], bfv, acc2[1][nf], 0, 0, 0);
    }
  }
  #pragma unroll
  for (int mf = 0; mf < 2; ++mf)
    #pragma unroll
    for (int nf = 0; nf < 4; ++nf) {
      const int n = wn * 64 + nf * 16 + lrow;
      #pragma unroll
      for (int r = 0; r < 4; ++r) {
        const int m = bm0 + wm * 32 + mf * 16 + kq * 4 + r;
        if (m < NNODES && n < NT) out_node[m * NT + n] = acc2[mf][nf][r] + nb3[n];
      }
    }
}

// ---------------- K3: persistent pipelined gather-GEMM ----------------
// 512 blocks x 128 threads, grid-stride over 25000 16-edge tiles.
// LDS raw[2][32KB]: per buf, src 16x1KB then dst 16x1KB; staged by global_load_lds
// (width 16, zero VGPR cost), source-swizzled (j^edge) so compute-side
// ds_read_b128 at stride 128B is conflict-free. Counted vmcnt keeps next tile's
// 32KB in flight across barriers. wave0 = type MLP, wave1 = dir MLP.
__global__ __launch_bounds__(128) void k3_edge(
    const short* __restrict__ Pall, const int* __restrict__ eidx,
    const short* __restrict__ Wt2cat,
    const float* __restrict__ tb2, const float* __restrict__ db2,
    const float* __restrict__ tW3, const float* __restrict__ dW3p,
    const float* __restrict__ tb3, const float* __restrict__ db3,
    float* __restrict__ out_t, float* __restrict__ out_d)
{
  __shared__ short raw[2][16384];              // 64 KB total -> 2 blocks/CU
  const int t_ = threadIdx.x;
  const int wid = t_ >> 6, lane = t_ & 63;
  const int er  = lane & 15, kq = lane >> 4;   // mfma coords: er = edge(A)/ncol(B,D)
  const int er7 = er & 7,  w16 = er >> 3;
  const int sl_e = lane >> 3;                  // staging: edge slot in wave (0..7)
  const int jj   = lane & 7;                   //          chunk slot (0..7)
  const int jg   = jj ^ sl_e;                  //          swizzled global chunk
  const int es   = wid * 8 + sl_e;             // edge slot within 16-edge tile

  const int P0    = wid ? 512 : 0;             // byte offset of this wave's half-row
  const int wrow0 = wid ? 256 : 128;           // Wt2cat row base
  const float* b2 = wid ? db2 : tb2;
  const float* b3 = wid ? db3 : tb3;
  const float* W3 = wid ? dW3p : tW3;          // f32 [128][4]

  int t = blockIdx.x;

  // ---- prologue: stage tile t into buf0; prefetch idx for t+G ----
  {
    int sA = eidx[t * 16 + es], dA = eidx[NEDGES + t * 16 + es];
    const short* gs = Pall + (size_t)sA * 1024 + jg * 8;
    const short* gd = Pall + (size_t)dA * 1024 + 512 + jg * 8;
    #pragma unroll
    for (int c = 0; c < 8; ++c)
      __builtin_amdgcn_global_load_lds(
        (const __attribute__((address_space(1))) void*)(gs + c * 64),
        (__attribute__((address_space(3))) void*)&raw[0][wid * 4096 + c * 512], 16, 0, 0);
    #pragma unroll
    for (int c = 0; c < 8; ++c)
      __builtin_amdgcn_global_load_lds(
        (const __attribute__((address_space(1))) void*)(gd + c * 64),
        (__attribute__((address_space(3))) void*)&raw[0][8192 + wid * 4096 + c * 512], 16, 0, 0);
  }
  int t1 = t + K3_GRID; if (t1 > K3_TILES - 1) t1 = K3_TILES - 1;
  int iNs = eidx[t1 * 16 + es], iNd = eidx[NEDGES + t1 * 16 + es];

  int parity = 0;
  while (t < K3_TILES) {
    // ---- stage tile t+G into buf[parity^1] (16 global_load_lds, in flight thru compute) ----
    {
      const short* gs = Pall + (size_t)iNs * 1024 + jg * 8;
      const short* gd = Pall + (size_t)iNd * 1024 + 512 + jg * 8;
      const int bo = (parity ^ 1) ? 1 : 0;
      #pragma unroll
      for (int c = 0; c < 8; ++c)
        __builtin_amdgcn_global_load_lds(
          (const __attribute__((address_space(1))) void*)(gs + c * 64),
          (__attribute__((address_space(3))) void*)&raw[bo][wid * 4096 + c * 512], 16, 0, 0);
      #pragma unroll
      for (int c = 0; c < 8; ++c)
        __builtin_amdgcn_global_load_lds(
          (const __attribute__((address_space(1))) void*)(gd + c * 64),
          (__attribute__((address_space(3))) void*)&raw[bo][8192 + wid * 4096 + c * 512], 16, 0, 0);
    }
    // ---- idx prefetch for t+2G ----
    {
      int tnn = t + 2 * K3_GRID; if (tnn > K3_TILES - 1) tnn = K3_TILES - 1;
      iNs = eidx[tnn * 16 + es]; iNd = eidx[NEDGES + tnn * 16 + es];
    }
    // ---- counted drain: everything older than {16 stage + 2 idx} is done ----
    asm volatile("s_waitcnt vmcnt(18)" ::: "memory");
    __builtin_amdgcn_s_barrier();

    // ---- compute tile t from buf[parity] ----
    {
      const short* R = &raw[parity][0];
      f4 acc[8];
      #pragma unroll
      for (int nf = 0; nf < 8; ++nf) acc[nf] = (f4){0.f, 0.f, 0.f, 0.f};
      #pragma unroll
      for (int kc = 0; kc < 8; ++kc) {
        const int b = P0 + kc * 64 + kq * 16;      // byte in staged 1KB half
        const int c = b >> 7;
        const int jw = (b >> 4) & 7;
        const int off = w16 * 4096 + c * 512 + er7 * 64 + (jw ^ er7) * 8;
        short8 sv = *(const short8*)(R + off);
        short8 dv = *(const short8*)(R + 8192 + off);
        short8 af;
        #pragma unroll
        for (int x = 0; x < 8; ++x) {
          float f = bf2f(sv[x]) + bf2f(dv[x]);
          af[x] = f2bf(f > 0.f ? f : 0.f);
        }
        #pragma unroll
        for (int nf = 0; nf < 8; ++nf) {
          short8 bfv = *(const short8*)(Wt2cat + (wrow0 + nf * 16 + er) * 256 + kc * 32 + kq * 8);
          acc[nf] = __builtin_amdgcn_mfma_f32_16x16x32_bf16(af, bfv, acc[nf], 0, 0, 0);
        }
      }
      // h2 = relu(acc + b2); layer-3 partials over this lane's h2 column (nf*16+er)
      float p[4][4];
      #pragma unroll
      for (int n = 0; n < 4; ++n)
        #pragma unroll
        for (int r = 0; r < 4; ++r) p[n][r] = 0.f;
      #pragma unroll
      for (int nf = 0; nf < 8; ++nf) {
        const float bb = b2[nf * 16 + er];
        f4 wv = ((const f4*)W3)[nf * 16 + er];
        #pragma unroll
        for (int r = 0; r < 4; ++r) {
          float h = acc[nf][r] + bb; h = h > 0.f ? h : 0.f;
          #pragma unroll
          for (int n = 0; n < 4; ++n) p[n][r] += h * wv[n];
        }
      }
      #pragma unroll
      for (int mask = 1; mask < 16; mask <<= 1)
        #pragma unroll
        for (int n = 0; n < 4; ++n)
          #pragma unroll
          for (int r = 0; r < 4; ++r) p[n][r] += __shfl_xor(p[n][r], mask, 64);

      const int e0 = t * 16;
      if (wid == 0) {
        if (er < 4) {
          const float bb = b3[er];
          #pragma unroll
          for (int r = 0; r < 4; ++r) out_t[(e0 + kq * 4 + r) * 4 + er] = p[er][r] + bb;
        }
      } else {
        if (er < 3) {
          const float bb = b3[er];
          #pragma unroll
          for (int r = 0; r < 4; ++r) out_d[(e0 + kq * 4 + r) * 3 + er] = p[er][r] + bb;
        }
      }
    }
    asm volatile("s_waitcnt lgkmcnt(0)" ::: "memory");
    __builtin_amdgcn_s_barrier();
    parity ^= 1;
    t += K3_GRID;
  }
}

extern "C" void kernel_launch(void* const* d_in, const int* in_sizes, int n_in,
                              void* d_out, int out_size, void* d_ws, size_t ws_size,
                              hipStream_t stream)
{
  const float* lat = (const float*)d_in[0];
  const float* pos = (const float*)d_in[1];
  const int* batch = (const int*)d_in[2];
  const int* eidx  = (const int*)d_in[3];
  const float* nW1 = (const float*)d_in[4];  const float* nb1 = (const float*)d_in[5];
  const float* nW2 = (const float*)d_in[6];  const float* nb2 = (const float*)d_in[7];
  const float* nW3 = (const float*)d_in[8];  const float* nb3 = (const float*)d_in[9];
  const float* tW1 = (const float*)d_in[10]; const float* tb1 = (const float*)d_in[11];
  const float* tW2 = (const float*)d_in[12]; const float* tb2 = (const float*)d_in[13];
  const float* tW3 = (const float*)d_in[14]; const float* tb3 = (const float*)d_in[15];
  const float* dW1 = (const float*)d_in[16]; const float* db1 = (const float*)d_in[17];
  const float* dW2 = (const float*)d_in[18]; const float* db2 = (const float*)d_in[19];
  const float* dW3 = (const float*)d_in[20]; const float* db3 = (const float*)d_in[21];

  char* ws = (char*)d_ws;
  short* latent_bf = (short*)(ws + 0);          //   1,048,576 B
  short* pos_bf    = (short*)(ws + 1048576);    //   1,600,000 B
  short* Wtcat     = (short*)(ws + 2648576);    //     737,280 B
  short* Wt2cat    = (short*)(ws + 3385856);    //     196,608 B
  short* Wt3n      = (short*)(ws + 3582464);    //      32,768 B
  float* dW3p      = (float*)(ws + 3615232);    //       2,048 B
  short* h1_node   = (short*)(ws + 3617280);    //  51,200,000 B
  short* Pall      = (short*)(ws + 54817280);   // 204,800,000 B  -> total ~259.6 MB

  float* out_node = (float*)d_out;
  float* out_t = out_node + (size_t)NNODES * NT;
  float* out_d = out_t + (size_t)NEDGES * 4;

  prep_kernel<<<7063, 256, 0, stream>>>(lat, pos, nW1, tW1, dW1, nW2, tW2, dW2,
                                        nW3, dW3, latent_bf, pos_bf, Wtcat,
                                        Wt2cat, Wt3n, dW3p);
  k1_gemm<<<dim3(1563, 10), 256, 0, stream>>>(latent_bf, pos_bf, batch, Wtcat,
                                              nb1, tb1, db1, h1_node, Pall);
  k2_node_tail<<<1563, 256, 0, stream>>>(h1_node, Wt2cat, Wt3n, nb2, nb3, out_node);
  k3_edge<<<K3_GRID, 128, 0, stream>>>(Pall, eidx, Wt2cat,
                                       tb2, db2, tW3, dW3p, tb3, db3, out_t, out_d);
}

// Round 6
// 706.675 us; speedup vs baseline: 1.2104x; 1.1445x over previous
//
#include <hip/hip_runtime.h>
#include <hip/hip_bf16.h>
#include <stdint.h>

#define LATF 256
#define NT 119
#define NNODES 100000
#define NEDGES 400000
#define NBUCK 100352          // 392*256, >= NNODES
#define NT3 12500             // k3 tiles of 32 edges

typedef __attribute__((ext_vector_type(8))) short short8;
typedef __attribute__((ext_vector_type(4))) float f4;

__device__ __forceinline__ float bf2f(short u) {
  union { uint32_t i; float f; } v; v.i = ((uint32_t)(uint16_t)u) << 16; return v.f;
}
__device__ __forceinline__ short f2bf(float f) {
  union { float f; uint32_t i; } v; v.f = f;
  uint32_t r = (v.i + 0x7fffu + ((v.i >> 16) & 1u)) >> 16;
  return (short)(uint16_t)r;
}

// ---------------- prep: cast + build transposed weight layouts ----------------
__global__ __launch_bounds__(256) void prep_kernel(
    const float* __restrict__ lat, const float* __restrict__ pos,
    const float* __restrict__ nW1, const float* __restrict__ tW1, const float* __restrict__ dW1,
    const float* __restrict__ nW2, const float* __restrict__ tW2, const float* __restrict__ dW2,
    const float* __restrict__ nW3, const float* __restrict__ tW3, const float* __restrict__ dW3,
    short* __restrict__ latent_bf, short* __restrict__ pos_bf,
    short* __restrict__ Wtcat, short* __restrict__ Wt2cat,
    short* __restrict__ Wt3n, short* __restrict__ Wt3t, short* __restrict__ Wt3d)
{
  int i = blockIdx.x * 256 + threadIdx.x;
  if (i < 524288) { latent_bf[i] = f2bf(lat[i]); return; }
  i -= 524288;
  if (i < 800000) { pos_bf[i] = f2bf(pos[i]); return; }
  i -= 800000;
  if (i < 1280 * 288) {               // Wtcat[n][k], n-major, K padded 264->288
    int n = i / 288, k = i % 288;
    float v = 0.f;
    if (k < 264) {
      if (n < 256)       v = nW1[k * 256 + n];
      else if (n < 512)  v = tW1[k * 256 + (n - 256)];
      else if (n < 768)  v = tW1[(264 + k) * 256 + (n - 512)];
      else if (n < 1024) v = dW1[k * 256 + (n - 768)];
      else               v = dW1[(264 + k) * 256 + (n - 1024)];
    }
    Wtcat[n * 288 + k] = f2bf(v);
    return;
  }
  i -= 1280 * 288;
  if (i < 384 * 256) {                // Wt2cat[n][k]: rows 0-127 nW2, 128-255 tW2, 256-383 dW2
    int n = i / 256, k = i % 256;
    float v = (n < 128) ? nW2[k * 128 + n] : (n < 256) ? tW2[k * 128 + (n - 128)]
                                                       : dW2[k * 128 + (n - 256)];
    Wt2cat[n * 256 + k] = f2bf(v);
    return;
  }
  i -= 384 * 256;
  if (i < 128 * 128) {                // Wt3n[n][k], n padded 119->128
    int n = i / 128, k = i % 128;
    Wt3n[i] = (n < NT) ? f2bf(nW3[k * NT + n]) : (short)0;
    return;
  }
  i -= 128 * 128;
  if (i < 4 * 128) { int n = i / 128, k = i % 128; Wt3t[i] = f2bf(tW3[k * 4 + n]); return; }
  i -= 512;
  if (i < 3 * 128) { int n = i / 128, k = i % 128; Wt3d[i] = f2bf(dW3[k * 3 + n]); return; }
}

// ---------------- counting sort of edges by src node ----------------
__global__ __launch_bounds__(256) void kzero(int* __restrict__ cnt) {
  cnt[blockIdx.x * 256 + threadIdx.x] = 0;
}
__global__ __launch_bounds__(256) void khist(const int* __restrict__ eidx, int* __restrict__ cnt) {
  int e = blockIdx.x * 256 + threadIdx.x;
  if (e < NEDGES) atomicAdd(&cnt[eidx[e]], 1);
}
__global__ __launch_bounds__(256) void kscan1(int* __restrict__ cnt, int* __restrict__ bsum) {
  __shared__ int s[256];
  const int t = threadIdx.x;
  const int i = blockIdx.x * 256 + t;
  int x = cnt[i];
  s[t] = x;
  __syncthreads();
  #pragma unroll
  for (int off = 1; off < 256; off <<= 1) {
    int y = (t >= off) ? s[t - off] : 0;
    __syncthreads();
    s[t] += y;
    __syncthreads();
  }
  cnt[i] = s[t] - x;                      // in-block exclusive prefix
  if (t == 255) bsum[blockIdx.x] = s[t];  // block total
}
__global__ __launch_bounds__(512) void kscan2(int* __restrict__ bsum) {
  __shared__ int s[512];
  const int t = threadIdx.x;
  int x = (t < 392) ? bsum[t] : 0;
  s[t] = x;
  __syncthreads();
  #pragma unroll
  for (int off = 1; off < 512; off <<= 1) {
    int y = (t >= off) ? s[t - off] : 0;
    __syncthreads();
    s[t] += y;
    __syncthreads();
  }
  if (t < 392) bsum[t] = s[t] - x;        // exclusive block bases
}
__global__ __launch_bounds__(256) void kscatter(
    const int* __restrict__ eidx, int* __restrict__ cnt,
    const int* __restrict__ bsum, int* __restrict__ perm) {
  int e = blockIdx.x * 256 + threadIdx.x;
  if (e < NEDGES) {
    int sNode = eidx[e];
    int p = atomicAdd(&cnt[sNode], 1) + bsum[sNode >> 8];
    perm[p] = e;
  }
}

// ---------------- K1: nodeFeat x [nW1 | tW1_src | tW1_dst | dW1_src | dW1_dst] ----------------
// M=100000, K=288 (pad), N=1280. BM=64, BN=128, 4 waves (2x2), each wave 32x64.
// Epilogue writes Pall layout [t_src | d_src | t_dst | d_dst]; tb1 folded into t_src,
// db1 into d_src.
__global__ __launch_bounds__(256) void k1_gemm(
    const short* __restrict__ latent_bf, const short* __restrict__ pos_bf,
    const int* __restrict__ batch, const short* __restrict__ Wtcat,
    const float* __restrict__ nb1, const float* __restrict__ tb1, const float* __restrict__ db1,
    short* __restrict__ h1_node, short* __restrict__ Pall)
{
  __shared__ short As[64 * 40];
  const int t = threadIdx.x;
  const int bm0 = blockIdx.x * 64;
  const int n0 = blockIdx.y * 128;
  const int wid = t >> 6, lane = t & 63;
  const int wm = wid >> 1, wn = wid & 1;
  const int lrow = lane & 15, kq = lane >> 4;

  const int sr = t >> 2, sq = t & 3;
  const int m_stage = bm0 + sr;
  const bool svalid = (m_stage < NNODES);
  const int g = svalid ? batch[m_stage] : 0;

  f4 acc[2][4];
  #pragma unroll
  for (int a = 0; a < 2; ++a)
    #pragma unroll
    for (int b = 0; b < 4; ++b) acc[a][b] = (f4){0.f, 0.f, 0.f, 0.f};

  for (int kc = 0; kc < 9; ++kc) {
    const int k0 = kc * 32;
    short8 av = {0, 0, 0, 0, 0, 0, 0, 0};
    if (svalid) {
      if (k0 < 256)      av = *(const short8*)(latent_bf + g * 256 + k0 + sq * 8);
      else if (sq == 0)  av = *(const short8*)(pos_bf + m_stage * 8);
    }
    *(short8*)(As + sr * 40 + sq * 8) = av;
    __syncthreads();

    short8 af[2];
    #pragma unroll
    for (int mf = 0; mf < 2; ++mf)
      af[mf] = *(const short8*)(As + (wm * 32 + mf * 16 + lrow) * 40 + kq * 8);
    #pragma unroll
    for (int nf = 0; nf < 4; ++nf) {
      const int ncol = n0 + wn * 64 + nf * 16 + lrow;
      short8 bfv = *(const short8*)(Wtcat + ncol * 288 + k0 + kq * 8);
      acc[0][nf] = __builtin_amdgcn_mfma_f32_16x16x32_bf16(af[0], bfv, acc[0][nf], 0, 0, 0);
      acc[1][nf] = __builtin_amdgcn_mfma_f32_16x16x32_bf16(af[1], bfv, acc[1][nf], 0, 0, 0);
    }
    __syncthreads();
  }

  #pragma unroll
  for (int mf = 0; mf < 2; ++mf)
    #pragma unroll
    for (int nf = 0; nf < 4; ++nf) {
      const int nglob = n0 + wn * 64 + nf * 16 + lrow;
      #pragma unroll
      for (int r = 0; r < 4; ++r) {
        const int m = bm0 + wm * 32 + mf * 16 + kq * 4 + r;
        if (m < NNODES) {
          float v = acc[mf][nf][r];
          if (nglob < 256) {
            float h = v + nb1[nglob];
            h1_node[m * 256 + nglob] = f2bf(h > 0.f ? h : 0.f);
          } else {
            const int pc = nglob - 256;
            float vv = v;
            int newc = pc;
            if (pc < 256)       { vv += tb1[pc]; }                        // t_src -> 0:256
            else if (pc < 512)  { newc = pc + 256; }                      // t_dst -> 512:768
            else if (pc < 768)  { vv += db1[pc - 512]; newc = pc - 256; } // d_src -> 256:512
            Pall[m * 1024 + newc] = f2bf(vv);
          }
        }
      }
    }
}

// ---------------- K2: node tail 256 -> 128(relu) -> 119 ----------------
__global__ __launch_bounds__(256) void k2_node_tail(
    const short* __restrict__ h1_node, const short* __restrict__ Wt2cat,
    const short* __restrict__ Wt3n, const float* __restrict__ nb2,
    const float* __restrict__ nb3, float* __restrict__ out_node)
{
  __shared__ short h2s[64 * 136];
  const int t = threadIdx.x;
  const int bm0 = blockIdx.x * 64;
  const int wid = t >> 6, lane = t & 63;
  const int wm = wid >> 1, wn = wid & 1;
  const int lrow = lane & 15, kq = lane >> 4;

  f4 acc[2][4];
  #pragma unroll
  for (int a = 0; a < 2; ++a)
    #pragma unroll
    for (int b = 0; b < 4; ++b) acc[a][b] = (f4){0.f, 0.f, 0.f, 0.f};

  #pragma unroll
  for (int kc = 0; kc < 8; ++kc) {
    short8 af[2];
    #pragma unroll
    for (int mf = 0; mf < 2; ++mf) {
      const int m = bm0 + wm * 32 + mf * 16 + lrow;
      if (m < NNODES) af[mf] = *(const short8*)(h1_node + m * 256 + kc * 32 + kq * 8);
      else            af[mf] = (short8){0, 0, 0, 0, 0, 0, 0, 0};
    }
    #pragma unroll
    for (int nf = 0; nf < 4; ++nf) {
      const int ncol = wn * 64 + nf * 16 + lrow;
      short8 bfv = *(const short8*)(Wt2cat + ncol * 256 + kc * 32 + kq * 8);
      acc[0][nf] = __builtin_amdgcn_mfma_f32_16x16x32_bf16(af[0], bfv, acc[0][nf], 0, 0, 0);
      acc[1][nf] = __builtin_amdgcn_mfma_f32_16x16x32_bf16(af[1], bfv, acc[1][nf], 0, 0, 0);
    }
  }
  #pragma unroll
  for (int mf = 0; mf < 2; ++mf)
    #pragma unroll
    for (int nf = 0; nf < 4; ++nf) {
      const int n = wn * 64 + nf * 16 + lrow;
      #pragma unroll
      for (int r = 0; r < 4; ++r) {
        const int ml = wm * 32 + mf * 16 + kq * 4 + r;
        float h = acc[mf][nf][r] + nb2[n];
        h2s[ml * 136 + n] = f2bf(h > 0.f ? h : 0.f);
      }
    }
  __syncthreads();

  f4 acc2[2][4];
  #pragma unroll
  for (int a = 0; a < 2; ++a)
    #pragma unroll
    for (int b = 0; b < 4; ++b) acc2[a][b] = (f4){0.f, 0.f, 0.f, 0.f};

  #pragma unroll
  for (int kc = 0; kc < 4; ++kc) {
    short8 af[2];
    #pragma unroll
    for (int mf = 0; mf < 2; ++mf)
      af[mf] = *(const short8*)(h2s + (wm * 32 + mf * 16 + lrow) * 136 + kc * 32 + kq * 8);
    #pragma unroll
    for (int nf = 0; nf < 4; ++nf) {
      const int ncol = wn * 64 + nf * 16 + lrow;
      short8 bfv = *(const short8*)(Wt3n + ncol * 128 + kc * 32 + kq * 8);
      acc2[0][nf] = __builtin_amdgcn_mfma_f32_16x16x32_bf16(af[0], bfv, acc2[0][nf], 0, 0, 0);
      acc2[1][nf] = __builtin_amdgcn_mfma_f32_16x16x32_bf16(af[1], bfv, acc2[1][nf], 0, 0, 0);
    }
  }
  #pragma unroll
  for (int mf = 0; mf < 2; ++mf)
    #pragma unroll
    for (int nf = 0; nf < 4; ++nf) {
      const int n = wn * 64 + nf * 16 + lrow;
      #pragma unroll
      for (int r = 0; r < 4; ++r) {
        const int m = bm0 + wm * 32 + mf * 16 + kq * 4 + r;
        if (m < NNODES && n < NT) out_node[m * NT + n] = acc2[mf][nf][r] + nb3[n];
      }
    }
}

// ---------------- K3: edge tail over src-sorted perm, combined gather session ----------------
// Pall layout: [t_src(0:256) | d_src(256:512) | t_dst(512:768) | d_dst(768:1024)].
// Per edge: src cols 0:512 (1KB contiguous) + dst cols 512:1024 (1KB contiguous).
// Edges processed in src-sorted order (perm) -> src gathers are L1/L2-local.
// Tile->block via bijective XCD-chunked map so each XCD walks a contiguous src range.
__global__ __launch_bounds__(256) void k3_edge(
    const short* __restrict__ Pall, const int* __restrict__ eidx,
    const int* __restrict__ perm,
    const short* __restrict__ Wt2cat, const short* __restrict__ Wt3t, const short* __restrict__ Wt3d,
    const float* __restrict__ tb2, const float* __restrict__ tb3,
    const float* __restrict__ db2, const float* __restrict__ db3,
    float* __restrict__ out_t, float* __restrict__ out_d)
{
  __shared__ short h1[32 * 520];               // 33,280 B -> 4 blocks/CU
  const int t = threadIdx.x;
  const int wid = t >> 6, lane = t & 63;
  // bijective XCD-chunked tile map: 12500 = 4*1563 + 4*1562
  const int xcd = blockIdx.x & 7, chunk = blockIdx.x >> 3;
  const int tile = (xcd < 4) ? xcd * 1563 + chunk : 6252 + (xcd - 4) * 1562 + chunk;
  const int er = t >> 3, j = t & 7;            // gather: 8 lanes per edge
  const int lrow = lane & 15, kq = lane >> 4;  // mfma lane coords

  const int eid = perm[tile * 32 + er];
  const int s_idx = eidx[eid];
  const int d_idx = eidx[NEDGES + eid];

  // ---- gather both phases: 8 lanes/edge, per-instr 8 contiguous 128B lines ----
  {
    const short* Ps = Pall + (long)s_idx * 1024 + j * 8;
    const short* Pd = Pall + (long)d_idx * 1024 + 512 + j * 8;
    short8 sv[8], dv[8];
    #pragma unroll
    for (int c = 0; c < 8; ++c) sv[c] = *(const short8*)(Ps + c * 64);
    #pragma unroll
    for (int c = 0; c < 8; ++c) dv[c] = *(const short8*)(Pd + c * 64);
    #pragma unroll
    for (int c = 0; c < 8; ++c) {
      short8 o;
      #pragma unroll
      for (int x = 0; x < 8; ++x) {
        float f = bf2f(sv[c][x]) + bf2f(dv[c][x]);
        o[x] = f2bf(f > 0.f ? f : 0.f);
      }
      *(short8*)(h1 + er * 520 + c * 64 + j * 8) = o;
    }
  }
  __syncthreads();

  // ---- layer2 TYPE: h1[:,0:256] @ tW2 (Wt2cat rows 128:256). M=32, wave owns 32 N-cols.
  f4 acc_t[2][2];
  #pragma unroll
  for (int a = 0; a < 2; ++a)
    #pragma unroll
    for (int b = 0; b < 2; ++b) acc_t[a][b] = (f4){0.f, 0.f, 0.f, 0.f};
  #pragma unroll
  for (int kc = 0; kc < 8; ++kc) {
    short8 a0 = *(const short8*)(h1 + lrow * 520 + kc * 32 + kq * 8);
    short8 a1 = *(const short8*)(h1 + (16 + lrow) * 520 + kc * 32 + kq * 8);
    #pragma unroll
    for (int nf = 0; nf < 2; ++nf) {
      short8 bfv = *(const short8*)(Wt2cat + (128 + wid * 32 + nf * 16 + lrow) * 256 + kc * 32 + kq * 8);
      acc_t[0][nf] = __builtin_amdgcn_mfma_f32_16x16x32_bf16(a0, bfv, acc_t[0][nf], 0, 0, 0);
      acc_t[1][nf] = __builtin_amdgcn_mfma_f32_16x16x32_bf16(a1, bfv, acc_t[1][nf], 0, 0, 0);
    }
  }
  __syncthreads();   // all waves done reading h1_t before overwrite

  // ---- h2_t = relu(acc_t + tb2) -> cols 0:128 (over dead h1_t) ----
  #pragma unroll
  for (int mf = 0; mf < 2; ++mf)
    #pragma unroll
    for (int nf = 0; nf < 2; ++nf) {
      const int n2 = wid * 32 + nf * 16 + lrow;
      const float bb = tb2[n2];
      #pragma unroll
      for (int rr = 0; rr < 4; ++rr) {
        float h = acc_t[mf][nf][rr] + bb;
        h1[(mf * 16 + kq * 4 + rr) * 520 + n2] = f2bf(h > 0.f ? h : 0.f);
      }
    }

  // ---- layer2 DIR: h1[:,256:512] @ dW2 (Wt2cat rows 256:384) ----
  f4 acc_d[2][2];
  #pragma unroll
  for (int a = 0; a < 2; ++a)
    #pragma unroll
    for (int b = 0; b < 2; ++b) acc_d[a][b] = (f4){0.f, 0.f, 0.f, 0.f};
  #pragma unroll
  for (int kc = 0; kc < 8; ++kc) {
    short8 a0 = *(const short8*)(h1 + lrow * 520 + 256 + kc * 32 + kq * 8);
    short8 a1 = *(const short8*)(h1 + (16 + lrow) * 520 + 256 + kc * 32 + kq * 8);
    #pragma unroll
    for (int nf = 0; nf < 2; ++nf) {
      short8 bfv = *(const short8*)(Wt2cat + (256 + wid * 32 + nf * 16 + lrow) * 256 + kc * 32 + kq * 8);
      acc_d[0][nf] = __builtin_amdgcn_mfma_f32_16x16x32_bf16(a0, bfv, acc_d[0][nf], 0, 0, 0);
      acc_d[1][nf] = __builtin_amdgcn_mfma_f32_16x16x32_bf16(a1, bfv, acc_d[1][nf], 0, 0, 0);
    }
  }

  // ---- h2_d = relu(acc_d + db2) -> cols 128:256 (over dead h1_t upper half) ----
  #pragma unroll
  for (int mf = 0; mf < 2; ++mf)
    #pragma unroll
    for (int nf = 0; nf < 2; ++nf) {
      const int n2 = wid * 32 + nf * 16 + lrow;
      const float bb = db2[n2];
      #pragma unroll
      for (int rr = 0; rr < 4; ++rr) {
        float h = acc_d[mf][nf][rr] + bb;
        h1[(mf * 16 + kq * 4 + rr) * 520 + 128 + n2] = f2bf(h > 0.f ? h : 0.f);
      }
    }
  __syncthreads();

  // ---- layer 3: 8 threads/edge, n=0..3 type, n=4..6 dir ----
  {
    const int e2 = t >> 3, n = t & 7;
    if (n < 7) {
      const bool isT = (n < 4);
      const int col = isT ? n : n - 4;
      const short* W3 = isT ? (Wt3t + col * 128) : (Wt3d + col * 128);
      const int base = e2 * 520 + (isT ? 0 : 128);
      float s = 0.f;
      #pragma unroll
      for (int kk = 0; kk < 16; ++kk) {
        short8 hv = *(const short8*)(h1 + base + kk * 8);
        short8 wv = *(const short8*)(W3 + kk * 8);
        #pragma unroll
        for (int x = 0; x < 8; ++x) s += bf2f(hv[x]) * bf2f(wv[x]);
      }
      const int eid2 = perm[tile * 32 + e2];
      if (isT) out_t[eid2 * 4 + col] = s + tb3[col];
      else     out_d[eid2 * 3 + col] = s + db3[col];
    }
  }
}

extern "C" void kernel_launch(void* const* d_in, const int* in_sizes, int n_in,
                              void* d_out, int out_size, void* d_ws, size_t ws_size,
                              hipStream_t stream)
{
  const float* lat = (const float*)d_in[0];
  const float* pos = (const float*)d_in[1];
  const int* batch = (const int*)d_in[2];
  const int* eidx  = (const int*)d_in[3];
  const float* nW1 = (const float*)d_in[4];  const float* nb1 = (const float*)d_in[5];
  const float* nW2 = (const float*)d_in[6];  const float* nb2 = (const float*)d_in[7];
  const float* nW3 = (const float*)d_in[8];  const float* nb3 = (const float*)d_in[9];
  const float* tW1 = (const float*)d_in[10]; const float* tb1 = (const float*)d_in[11];
  const float* tW2 = (const float*)d_in[12]; const float* tb2 = (const float*)d_in[13];
  const float* tW3 = (const float*)d_in[14]; const float* tb3 = (const float*)d_in[15];
  const float* dW1 = (const float*)d_in[16]; const float* db1 = (const float*)d_in[17];
  const float* dW2 = (const float*)d_in[18]; const float* db2 = (const float*)d_in[19];
  const float* dW3 = (const float*)d_in[20]; const float* db3 = (const float*)d_in[21];

  char* ws = (char*)d_ws;
  short* latent_bf = (short*)(ws + 0);          //   1,048,576 B
  short* pos_bf    = (short*)(ws + 1048576);    //   1,600,000 B
  short* Wtcat     = (short*)(ws + 2648576);    //     737,280 B
  short* Wt2cat    = (short*)(ws + 3385856);    //     196,608 B
  short* Wt3n      = (short*)(ws + 3582464);    //      32,768 B
  short* Wt3t      = (short*)(ws + 3615232);    //       1,024 B
  short* Wt3d      = (short*)(ws + 3616256);    //       1,024 B (768 used)
  short* h1_node   = (short*)(ws + 3617280);    //  51,200,000 B
  short* Pall      = (short*)(ws + 54817280);   // 204,800,000 B  -> total ~259.6 MB
  // sort scratch lives inside the h1_node region (dead once k2 finishes):
  int* perm = (int*)(ws + 3617280);             //   1,600,000 B
  int* cnt  = (int*)(ws + 3617280 + 1600000);   //     401,408 B (NBUCK)
  int* bsum = (int*)(ws + 3617280 + 2001408);   //       1,568 B (392)

  float* out_node = (float*)d_out;
  float* out_t = out_node + (size_t)NNODES * NT;
  float* out_d = out_t + (size_t)NEDGES * 4;

  prep_kernel<<<7065, 256, 0, stream>>>(lat, pos, nW1, tW1, dW1, nW2, tW2, dW2,
                                        nW3, tW3, dW3, latent_bf, pos_bf, Wtcat,
                                        Wt2cat, Wt3n, Wt3t, Wt3d);
  k1_gemm<<<dim3(1563, 10), 256, 0, stream>>>(latent_bf, pos_bf, batch, Wtcat,
                                              nb1, tb1, db1, h1_node, Pall);
  k2_node_tail<<<1563, 256, 0, stream>>>(h1_node, Wt2cat, Wt3n, nb2, nb3, out_node);
  // counting sort of edges by src (overwrites h1_node region, now dead)
  kzero<<<NBUCK / 256, 256, 0, stream>>>(cnt);
  khist<<<1563, 256, 0, stream>>>(eidx, cnt);
  kscan1<<<392, 256, 0, stream>>>(cnt, bsum);
  kscan2<<<1, 512, 0, stream>>>(bsum);
  kscatter<<<1563, 256, 0, stream>>>(eidx, cnt, bsum, perm);
  k3_edge<<<NT3, 256, 0, stream>>>(Pall, eidx, perm, Wt2cat, Wt3t, Wt3d,
                                   tb2, tb3, db2, db3, out_t, out_d);
}